// Round 1
// baseline (529.672 us; speedup 1.0000x reference)
//
#include <hip/hip_runtime.h>

#define NCONN 21
#define TPB 128

// Each thread owns one batch element: 63 input floats staged in LDS,
// normalized vectors u_e = (p_e - p_0)/|p_e - p_0| kept in LDS (own slot only).
// Output: out[(i*21 + j)*B + b] = angle(u_i, u_j); row i=0 / col j=0 are 0.
__global__ __launch_bounds__(TPB) void pv_kernel(const float* __restrict__ in,
                                                 float* __restrict__ out,
                                                 int B) {
    __shared__ float lds[TPB * 63];   // 32256 B -> ~5 blocks/CU
    const int tid = threadIdx.x;
    const long long blockBatch = (long long)blockIdx.x * TPB;

    // ---- Phase 1: coalesced cooperative staging (float4) ----
    const long long gBase  = blockBatch * 63;        // float index, %4 == 0
    const long long totalF4 = ((long long)B * 63) >> 2;
    const float4* in4 = (const float4*)in;
    const long long gBase4 = gBase >> 2;
    float4* lds4 = (float4*)lds;
    #pragma unroll
    for (int it = 0; it < 16; ++it) {
        int t = tid + it * TPB;                      // up to 2016 float4 per block
        if (t < (TPB * 63) / 4) {
            long long g4 = gBase4 + t;
            if (g4 < totalF4) lds4[t] = in4[g4];
        }
    }
    __syncthreads();

    const long long bl = blockBatch + tid;
    if (bl >= B) return;
    const int b = (int)bl;
    float* base = lds + tid * 63;

    // ---- Phase 2: normalize v_e in place (own slot; no sync needed) ----
    const float p0x = base[0], p0y = base[1], p0z = base[2];
    #pragma unroll
    for (int e = 1; e < NCONN; ++e) {
        float vx = base[3*e+0] - p0x;
        float vy = base[3*e+1] - p0y;
        float vz = base[3*e+2] - p0z;
        float d  = fmaf(vx, vx, fmaf(vy, vy, vz * vz));
        float r  = rsqrtf(d);
        base[3*e+0] = vx * r;
        base[3*e+1] = vy * r;
        base[3*e+2] = vz * r;
    }

    const size_t sB = (size_t)B;
    float* outb = out + b;

    // ---- i = 0 row: zeros (reference NaN->0) ----
    #pragma unroll
    for (int k = 0; k < NCONN; ++k) outb[(size_t)k * sB] = 0.0f;

    // ---- i in [1..20], two register chunks of 10 ----
    #pragma unroll
    for (int cc = 0; cc < 2; ++cc) {
        const int i0 = 1 + cc * 10;
        float uix[10], uiy[10], uiz[10];
        #pragma unroll
        for (int q = 0; q < 10; ++q) {
            uix[q] = base[3*(i0+q)+0];
            uiy[q] = base[3*(i0+q)+1];
            uiz[q] = base[3*(i0+q)+2];
        }
        // j = 0 column: zeros
        #pragma unroll
        for (int q = 0; q < 10; ++q)
            outb[(size_t)((i0+q)*NCONN) * sB] = 0.0f;

        for (int j = 1; j < NCONN; ++j) {
            const float ujx = base[3*j+0];
            const float ujy = base[3*j+1];
            const float ujz = base[3*j+2];
            #pragma unroll
            for (int q = 0; q < 10; ++q) {
                float c = fmaf(uix[q], ujx, fmaf(uiy[q], ujy, uiz[q] * ujz));
                // clamp; fminf first so NaN -> 1 -> acos = 0 (matches ref NaN->0)
                c = fmaxf(fminf(c, 1.0f), -1.0f);
                float t = fabsf(c);
                float s = sqrtf(1.0f - t);
                // Abramowitz & Stegun 4.4.45, |err| <= 6.7e-5
                float p = fmaf(t, -0.0187293f, 0.0742610f);
                p = fmaf(t, p, -0.2121144f);
                p = fmaf(t, p, 1.5707288f);
                float r = s * p;
                float ang = (c >= 0.0f) ? r : (3.14159265358979f - r);
                outb[(size_t)((i0+q)*NCONN + j) * sB] = ang;
            }
        }
    }
}

extern "C" void kernel_launch(void* const* d_in, const int* in_sizes, int n_in,
                              void* d_out, int out_size, void* d_ws, size_t ws_size,
                              hipStream_t stream) {
    const float* in = (const float*)d_in[0];
    float* out = (float*)d_out;
    const int B = in_sizes[0] / (NCONN * 3);   // 262144
    const int grid = (B + TPB - 1) / TPB;
    hipLaunchKernelGGL(pv_kernel, dim3(grid), dim3(TPB), 0, stream, in, out, B);
}